// Round 1
// baseline (24113.675 us; speedup 1.0000x reference)
//
#include <hip/hip_runtime.h>

#define BATCH 64
#define TSTEPS 256
#define INDIM 512
#define HDIM 1024
#define NBLK 256
#define NTHR 256
#define S0 48   // (512+1024)/32 k-steps, layer0
#define S1 64   // 2048/32, layer1
#define SF 32   // 1024/32, fc

typedef __bf16 bf16_t;
typedef __bf16 bf16x8 __attribute__((ext_vector_type(8)));
typedef float  f32x4  __attribute__((ext_vector_type(4)));

__device__ __forceinline__ float fast_sigmoid(float x){
  x = fminf(fmaxf(x, -30.f), 30.f);
  return 1.f / (1.f + __expf(-x));
}
__device__ __forceinline__ float fast_tanh(float x){
  x = fminf(fmaxf(x, -15.f), 15.f);
  float e = __expf(2.f * x);
  return (e - 1.f) / (e + 1.f);
}

// Sense-free monotonic grid barrier. cnt/gen zeroed by hipMemsetAsync before launch.
__device__ __forceinline__ void grid_barrier(unsigned* cnt, unsigned* gen, unsigned target){
  __syncthreads();
  if (threadIdx.x == 0){
    unsigned old = __hip_atomic_fetch_add(cnt, 1u, __ATOMIC_ACQ_REL, __HIP_MEMORY_SCOPE_AGENT);
    if (old == (unsigned)(NBLK - 1)){
      __hip_atomic_store(cnt, 0u, __ATOMIC_RELAXED, __HIP_MEMORY_SCOPE_AGENT);
      __hip_atomic_store(gen, target, __ATOMIC_RELEASE, __HIP_MEMORY_SCOPE_AGENT);
    } else {
      while (__hip_atomic_load(gen, __ATOMIC_ACQUIRE, __HIP_MEMORY_SCOPE_AGENT) < target){
        __builtin_amdgcn_s_sleep(1);
      }
    }
  }
  __syncthreads();
}

// One K-segment of the per-wave 16x16 GEMM. A from global (bf16, row-major, lda in
// elements already folded into aptr), W from LDS in fragment order:
// W[(step*64 + lane)*8 + j] = Wcol[n=lane&15][k = step*32 + (lane>>4)*8 + j].
template<int NS>
__device__ __forceinline__ void gemm_seg(const bf16_t* aptr, const bf16_t* Wl, int wOff, int lane,
                                         f32x4& acc0, f32x4& acc1){
#pragma unroll
  for (int s = 0; s < NS; ++s){
    uint4 av = *(const uint4*)(aptr + s * 32);
    bf16x8 af = __builtin_bit_cast(bf16x8, av);
    bf16x8 wf = *(const bf16x8*)(Wl + (wOff + s) * 512 + lane * 8);
    if (s & 1) acc1 = __builtin_amdgcn_mfma_f32_16x16x32_bf16(af, wf, acc1, 0, 0, 0);
    else       acc0 = __builtin_amdgcn_mfma_f32_16x16x32_bf16(af, wf, acc0, 0, 0, 0);
  }
}

// Persistent cooperative kernel: 256 blocks (1/CU) x 256 threads (4 waves).
// Block b owns hidden units {4b..4b+3} of both layers (16 gate cols each, LDS-resident
// bf16 weights), plus fc cols {16b..16b+15} for b<32. Wave w computes batch rows
// [16w,16w+16) via mfma_f32_16x16x32_bf16. c-state fp32 in LDS (never leaves block).
extern "C" __global__ void __launch_bounds__(NTHR, 1)
rnn_persistent(const float* __restrict__ hx,  const float* __restrict__ c0g,
               const float* __restrict__ Wih0, const float* __restrict__ Whh0,
               const float* __restrict__ bih0, const float* __restrict__ bhh0,
               const float* __restrict__ Wih1, const float* __restrict__ Whh1,
               const float* __restrict__ bih1, const float* __restrict__ bhh1,
               const float* __restrict__ fcw,  const float* __restrict__ fcb,
               float* __restrict__ out, void* ws)
{
  __shared__ bf16_t W0s[S0 * 512];        // 49152 B
  __shared__ bf16_t W1s[S1 * 512];        // 65536 B
  __shared__ bf16_t WFs[SF * 512];        // 32768 B
  __shared__ float  gates_s[4][16][17];   // per-wave 16x16 gate staging (+1 pad)
  __shared__ float  c0_l[BATCH][4];
  __shared__ float  c1_l[BATCH][4];
  __shared__ float  b0_l[16];
  __shared__ float  b1_l[16];
  __shared__ float  bf_l[16];

  const int b    = blockIdx.x;
  const int tid  = threadIdx.x;
  const int lane = tid & 63;
  const int wv   = tid >> 6;
  const int q    = lane >> 4;
  const int nl   = lane & 15;

  unsigned* cnt = (unsigned*)ws;
  unsigned* gen = cnt + 1;
  bf16_t* token = (bf16_t*)((char*)ws + 256);        // [64][512]
  bf16_t* h0b   = token + BATCH * INDIM;             // 2 x [64][1024]
  bf16_t* h1b   = h0b + 2 * BATCH * HDIM;            // 2 x [64][1024]

  // ---- init: swizzle this block's weight slice (fp32 -> bf16) into LDS ----
  // col for n_local: gate = nl>>2 (i,f,g,o), unit = 4b + (nl&3)
  for (int idx = tid; idx < S0 * 64; idx += NTHR){
    int s = idx >> 6, L = idx & 63;
    int qq = L >> 4, nn = L & 15;
    int col = (nn >> 2) * HDIM + b * 4 + (nn & 3);
    int k0 = s * 32 + qq * 8;
    const float* src = (k0 < INDIM) ? (Wih0 + col * INDIM + k0)
                                    : (Whh0 + col * HDIM + (k0 - INDIM));
    float4 u0 = ((const float4*)src)[0];
    float4 u1 = ((const float4*)src)[1];
    bf16_t* dst = W0s + idx * 8;
    dst[0]=(bf16_t)u0.x; dst[1]=(bf16_t)u0.y; dst[2]=(bf16_t)u0.z; dst[3]=(bf16_t)u0.w;
    dst[4]=(bf16_t)u1.x; dst[5]=(bf16_t)u1.y; dst[6]=(bf16_t)u1.z; dst[7]=(bf16_t)u1.w;
  }
  for (int idx = tid; idx < S1 * 64; idx += NTHR){
    int s = idx >> 6, L = idx & 63;
    int qq = L >> 4, nn = L & 15;
    int col = (nn >> 2) * HDIM + b * 4 + (nn & 3);
    int k0 = s * 32 + qq * 8;
    const float* src = (k0 < HDIM) ? (Wih1 + col * HDIM + k0)
                                   : (Whh1 + col * HDIM + (k0 - HDIM));
    float4 u0 = ((const float4*)src)[0];
    float4 u1 = ((const float4*)src)[1];
    bf16_t* dst = W1s + idx * 8;
    dst[0]=(bf16_t)u0.x; dst[1]=(bf16_t)u0.y; dst[2]=(bf16_t)u0.z; dst[3]=(bf16_t)u0.w;
    dst[4]=(bf16_t)u1.x; dst[5]=(bf16_t)u1.y; dst[6]=(bf16_t)u1.z; dst[7]=(bf16_t)u1.w;
  }
  if (b < 32){
    for (int idx = tid; idx < SF * 64; idx += NTHR){
      int s = idx >> 6, L = idx & 63;
      int qq = L >> 4, nn = L & 15;
      int col = b * 16 + nn;
      int k0 = s * 32 + qq * 8;
      const float* src = fcw + col * HDIM + k0;
      float4 u0 = ((const float4*)src)[0];
      float4 u1 = ((const float4*)src)[1];
      bf16_t* dst = WFs + idx * 8;
      dst[0]=(bf16_t)u0.x; dst[1]=(bf16_t)u0.y; dst[2]=(bf16_t)u0.z; dst[3]=(bf16_t)u0.w;
      dst[4]=(bf16_t)u1.x; dst[5]=(bf16_t)u1.y; dst[6]=(bf16_t)u1.z; dst[7]=(bf16_t)u1.w;
    }
    if (tid < 16) bf_l[tid] = fcb[b * 16 + tid];
  }
  if (tid < 16){
    int col = (tid >> 2) * HDIM + b * 4 + (tid & 3);
    b0_l[tid] = bih0[col] + bhh0[col];
    b1_l[tid] = bih1[col] + bhh1[col];
  }
  {
    int row = tid & 63, uu = tid >> 6;
    int unit = b * 4 + uu;
    c0_l[row][uu] = c0g[row * HDIM + unit];
    c1_l[row][uu] = c0g[BATCH * HDIM + row * HDIM + unit];
    h0b[row * HDIM + unit] = (bf16_t)hx[row * HDIM + unit];                 // parity 0
    h1b[row * HDIM + unit] = (bf16_t)hx[BATCH * HDIM + row * HDIM + unit];  // parity 0
  }
  {
    int g0 = b * NTHR + tid;
    if (g0 < BATCH * INDIM) token[g0] = (bf16_t)0.f;   // token0 = zeros
  }

  unsigned bargen = 1;
  grid_barrier(cnt, gen, bargen++);

#pragma unroll 1
  for (int t = 0; t < TSTEPS; ++t){
    const int rp = t & 1, wp = rp ^ 1;
    const bf16_t* h0r = h0b + rp * BATCH * HDIM;
    bf16_t*       h0w = h0b + wp * BATCH * HDIM;
    const bf16_t* h1r = h1b + rp * BATCH * HDIM;
    bf16_t*       h1w = h1b + wp * BATCH * HDIM;
    const int arow = wv * 16 + nl;   // A-operand row for this lane (m = lane&15)

    // ---- phase 1: layer-0 gates (A = [token | h0_prev]) + cell update ----
    {
      f32x4 acc0 = {0.f,0.f,0.f,0.f}, acc1 = {0.f,0.f,0.f,0.f};
      gemm_seg<16>(token + arow * INDIM + q * 8, W0s, 0,  lane, acc0, acc1);
      gemm_seg<32>(h0r   + arow * HDIM  + q * 8, W0s, 16, lane, acc0, acc1);
      f32x4 accv = acc0 + acc1;
      float bias = b0_l[nl];
#pragma unroll
      for (int r = 0; r < 4; ++r) gates_s[wv][q * 4 + r][nl] = accv[r] + bias;
      __syncthreads();
      int row = tid & 63, uu = tid >> 6;
      float pi = gates_s[row >> 4][row & 15][0 * 4 + uu];
      float pf = gates_s[row >> 4][row & 15][1 * 4 + uu];
      float pg = gates_s[row >> 4][row & 15][2 * 4 + uu];
      float po = gates_s[row >> 4][row & 15][3 * 4 + uu];
      float ig = fast_sigmoid(pi), fg = fast_sigmoid(pf);
      float gg = fast_tanh(pg),    og = fast_sigmoid(po);
      float c  = fg * c0_l[row][uu] + ig * gg;
      c0_l[row][uu] = c;
      h0w[row * HDIM + b * 4 + uu] = (bf16_t)(og * fast_tanh(c));
    }
    grid_barrier(cnt, gen, bargen++);

    // ---- phase 2: layer-1 gates (A = [h0_new | h1_prev]) + cell update ----
    {
      f32x4 acc0 = {0.f,0.f,0.f,0.f}, acc1 = {0.f,0.f,0.f,0.f};
      gemm_seg<32>(h0w + arow * HDIM + q * 8, W1s, 0,  lane, acc0, acc1);
      gemm_seg<32>(h1r + arow * HDIM + q * 8, W1s, 32, lane, acc0, acc1);
      f32x4 accv = acc0 + acc1;
      float bias = b1_l[nl];
#pragma unroll
      for (int r = 0; r < 4; ++r) gates_s[wv][q * 4 + r][nl] = accv[r] + bias;
      __syncthreads();
      int row = tid & 63, uu = tid >> 6;
      float pi = gates_s[row >> 4][row & 15][0 * 4 + uu];
      float pf = gates_s[row >> 4][row & 15][1 * 4 + uu];
      float pg = gates_s[row >> 4][row & 15][2 * 4 + uu];
      float po = gates_s[row >> 4][row & 15][3 * 4 + uu];
      float ig = fast_sigmoid(pi), fg = fast_sigmoid(pf);
      float gg = fast_tanh(pg),    og = fast_sigmoid(po);
      float c  = fg * c1_l[row][uu] + ig * gg;
      c1_l[row][uu] = c;
      h1w[row * HDIM + b * 4 + uu] = (bf16_t)(og * fast_tanh(c));
    }
    grid_barrier(cnt, gen, bargen++);

    // ---- phase 3: fc + sigmoid -> out[:,t,:] and next token (blocks 0..31) ----
    if (b < 32){
      f32x4 acc0 = {0.f,0.f,0.f,0.f}, acc1 = {0.f,0.f,0.f,0.f};
      gemm_seg<32>(h1w + arow * HDIM + q * 8, WFs, 0, lane, acc0, acc1);
      f32x4 accv = acc0 + acc1;
      int col = b * 16 + nl;
      float bias = bf_l[nl];
#pragma unroll
      for (int r = 0; r < 4; ++r){
        int m = wv * 16 + q * 4 + r;     // C/D: row = (lane>>4)*4 + reg, col = lane&15
        float v = fast_sigmoid(accv[r] + bias);
        out[m * (TSTEPS * INDIM) + t * INDIM + col] = v;
        token[m * INDIM + col] = (bf16_t)v;
      }
    }
    grid_barrier(cnt, gen, bargen++);
  }
}

extern "C" void kernel_launch(void* const* d_in, const int* in_sizes, int n_in,
                              void* d_out, int out_size, void* d_ws, size_t ws_size,
                              hipStream_t stream){
  const float* hx   = (const float*)d_in[1];
  const float* c0g  = (const float*)d_in[2];
  const float* Wih0 = (const float*)d_in[3];
  const float* Whh0 = (const float*)d_in[4];
  const float* bih0 = (const float*)d_in[5];
  const float* bhh0 = (const float*)d_in[6];
  const float* Wih1 = (const float*)d_in[7];
  const float* Whh1 = (const float*)d_in[8];
  const float* bih1 = (const float*)d_in[9];
  const float* bhh1 = (const float*)d_in[10];
  const float* fcw  = (const float*)d_in[11];
  const float* fcb  = (const float*)d_in[12];
  float* out = (float*)d_out;

  // zero barrier state (ws is poisoned 0xAA before every launch)
  hipMemsetAsync(d_ws, 0, 256, stream);

  void* args[] = { (void*)&hx, (void*)&c0g, (void*)&Wih0, (void*)&Whh0,
                   (void*)&bih0, (void*)&bhh0, (void*)&Wih1, (void*)&Whh1,
                   (void*)&bih1, (void*)&bhh1, (void*)&fcw, (void*)&fcb,
                   (void*)&out, (void*)&d_ws };
  hipLaunchCooperativeKernel((const void*)rnn_persistent, dim3(NBLK), dim3(NTHR),
                             args, 0, stream);
}

// Round 2
// 10077.608 us; speedup vs baseline: 2.3928x; 2.3928x over previous
//
#include <hip/hip_runtime.h>

#define BATCH 64
#define TSTEPS 256
#define INDIM 512
#define HDIM 1024
#define NBLK 256
#define NTHR 256
#define S0 48   // (512+1024)/32 k-steps, layer0
#define S1 64   // 2048/32, layer1
#define SF 32   // 1024/32, fc

typedef __bf16 bf16_t;
typedef __bf16 bf16x8 __attribute__((ext_vector_type(8)));
typedef float  f32x4  __attribute__((ext_vector_type(4)));

__device__ __forceinline__ float fast_sigmoid(float x){
  x = fminf(fmaxf(x, -30.f), 30.f);
  return 1.f / (1.f + __expf(-x));
}
__device__ __forceinline__ float fast_tanh(float x){
  x = fminf(fmaxf(x, -15.f), 15.f);
  float e = __expf(2.f * x);
  return (e - 1.f) / (e + 1.f);
}

// Flat distributed-flag barrier: block b stores generation to its own 64B slot
// (write-through, agent scope, no RMW); thread i polls slot i. No cache
// maintenance ops anywhere — all shared data is write-through atomic.
__device__ __forceinline__ void grid_barrier(unsigned* arrive, unsigned target){
  asm volatile("s_waitcnt vmcnt(0)" ::: "memory");  // drain this wave's write-through stores
  __syncthreads();                                   // all waves drained + LDS settled
  if (threadIdx.x == 0)
    __hip_atomic_store(&arrive[blockIdx.x * 16], target, __ATOMIC_RELAXED, __HIP_MEMORY_SCOPE_AGENT);
  unsigned* slot = &arrive[threadIdx.x * 16];
  while (__hip_atomic_load(slot, __ATOMIC_RELAXED, __HIP_MEMORY_SCOPE_AGENT) < target)
    __builtin_amdgcn_s_sleep(1);
  __syncthreads();
}

__device__ __forceinline__ bf16x8 load_frag_wt(const bf16_t* p){
  // 16B A-fragment as 2x8B agent-scope loads (coherent at L3, bypass stale L1/L2)
  unsigned long long* q = (unsigned long long*)p;
  unsigned long long a0 = __hip_atomic_load(q,     __ATOMIC_RELAXED, __HIP_MEMORY_SCOPE_AGENT);
  unsigned long long a1 = __hip_atomic_load(q + 1, __ATOMIC_RELAXED, __HIP_MEMORY_SCOPE_AGENT);
  ulonglong2 av; av.x = a0; av.y = a1;
  return __builtin_bit_cast(bf16x8, av);
}

// One K-segment run of the per-wave 16x16 GEMM. A from ws (write-through coherent),
// W from LDS in fragment order:
// W[(step*64 + lane)*8 + j] = Wcol[n=lane&15][k = step*32 + (lane>>4)*8 + j].
template<int NS>
__device__ __forceinline__ void gemm_seg(const bf16_t* aptr, const bf16_t* Wl, int wOff, int lane,
                                         f32x4& acc0, f32x4& acc1){
#pragma unroll
  for (int s = 0; s < NS; ++s){
    bf16x8 af = load_frag_wt(aptr + s * 32);
    bf16x8 wf = *(const bf16x8*)(Wl + (wOff + s) * 512 + lane * 8);
    if (s & 1) acc1 = __builtin_amdgcn_mfma_f32_16x16x32_bf16(af, wf, acc1, 0, 0, 0);
    else       acc0 = __builtin_amdgcn_mfma_f32_16x16x32_bf16(af, wf, acc0, 0, 0, 0);
  }
}

// Persistent cooperative kernel: 256 blocks (1/CU) x 256 threads (4 waves).
// Block b owns hidden units {4b..4b+3} of both layers (16 gate cols each, LDS-resident
// bf16 weights), plus fc cols {16b..16b+15} for b<32. Wave w computes batch rows
// [16w,16w+16) via mfma_f32_16x16x32_bf16. c-state fp32 in LDS (never leaves block).
extern "C" __global__ void __launch_bounds__(NTHR, 1)
rnn_persistent(const float* __restrict__ hx,  const float* __restrict__ c0g,
               const float* __restrict__ Wih0, const float* __restrict__ Whh0,
               const float* __restrict__ bih0, const float* __restrict__ bhh0,
               const float* __restrict__ Wih1, const float* __restrict__ Whh1,
               const float* __restrict__ bih1, const float* __restrict__ bhh1,
               const float* __restrict__ fcw,  const float* __restrict__ fcb,
               float* __restrict__ out, void* ws)
{
  __shared__ bf16_t W0s[S0 * 512];        // 49152 B
  __shared__ bf16_t W1s[S1 * 512];        // 65536 B
  __shared__ bf16_t WFs[SF * 512];        // 32768 B
  __shared__ float  gates_s[4][16][17];   // per-wave 16x16 gate staging (+1 pad)
  __shared__ float  c0_l[BATCH][4];
  __shared__ float  c1_l[BATCH][4];
  __shared__ __align__(8) bf16_t hstage[BATCH][4];   // pack 4x bf16 -> one 8B store
  __shared__ __align__(8) bf16_t tstage[BATCH][16];  // fc slice staging (b<32)
  __shared__ float  b0_l[16];
  __shared__ float  b1_l[16];
  __shared__ float  bf_l[16];

  const int b    = blockIdx.x;
  const int tid  = threadIdx.x;
  const int lane = tid & 63;
  const int wv   = tid >> 6;
  const int q    = lane >> 4;
  const int nl   = lane & 15;

  unsigned* arrive = (unsigned*)ws;                  // 256 slots x 64B = 16KB (+pad to 32KB)
  bf16_t* token = (bf16_t*)((char*)ws + 32768);      // [64][512]
  bf16_t* h0b   = token + BATCH * INDIM;             // 2 x [64][1024]
  bf16_t* h1b   = h0b + 2 * BATCH * HDIM;            // 2 x [64][1024]

  // ---- init: swizzle this block's weight slice (fp32 -> bf16) into LDS ----
  // col for n_local: gate = nl>>2 (i,f,g,o), unit = 4b + (nl&3)
  for (int idx = tid; idx < S0 * 64; idx += NTHR){
    int s = idx >> 6, L = idx & 63;
    int qq = L >> 4, nn = L & 15;
    int col = (nn >> 2) * HDIM + b * 4 + (nn & 3);
    int k0 = s * 32 + qq * 8;
    const float* src = (k0 < INDIM) ? (Wih0 + col * INDIM + k0)
                                    : (Whh0 + col * HDIM + (k0 - INDIM));
    float4 u0 = ((const float4*)src)[0];
    float4 u1 = ((const float4*)src)[1];
    bf16_t* dst = W0s + idx * 8;
    dst[0]=(bf16_t)u0.x; dst[1]=(bf16_t)u0.y; dst[2]=(bf16_t)u0.z; dst[3]=(bf16_t)u0.w;
    dst[4]=(bf16_t)u1.x; dst[5]=(bf16_t)u1.y; dst[6]=(bf16_t)u1.z; dst[7]=(bf16_t)u1.w;
  }
  for (int idx = tid; idx < S1 * 64; idx += NTHR){
    int s = idx >> 6, L = idx & 63;
    int qq = L >> 4, nn = L & 15;
    int col = (nn >> 2) * HDIM + b * 4 + (nn & 3);
    int k0 = s * 32 + qq * 8;
    const float* src = (k0 < HDIM) ? (Wih1 + col * HDIM + k0)
                                   : (Whh1 + col * HDIM + (k0 - HDIM));
    float4 u0 = ((const float4*)src)[0];
    float4 u1 = ((const float4*)src)[1];
    bf16_t* dst = W1s + idx * 8;
    dst[0]=(bf16_t)u0.x; dst[1]=(bf16_t)u0.y; dst[2]=(bf16_t)u0.z; dst[3]=(bf16_t)u0.w;
    dst[4]=(bf16_t)u1.x; dst[5]=(bf16_t)u1.y; dst[6]=(bf16_t)u1.z; dst[7]=(bf16_t)u1.w;
  }
  if (b < 32){
    for (int idx = tid; idx < SF * 64; idx += NTHR){
      int s = idx >> 6, L = idx & 63;
      int qq = L >> 4, nn = L & 15;
      int col = b * 16 + nn;
      int k0 = s * 32 + qq * 8;
      const float* src = fcw + col * HDIM + k0;
      float4 u0 = ((const float4*)src)[0];
      float4 u1 = ((const float4*)src)[1];
      bf16_t* dst = WFs + idx * 8;
      dst[0]=(bf16_t)u0.x; dst[1]=(bf16_t)u0.y; dst[2]=(bf16_t)u0.z; dst[3]=(bf16_t)u0.w;
      dst[4]=(bf16_t)u1.x; dst[5]=(bf16_t)u1.y; dst[6]=(bf16_t)u1.z; dst[7]=(bf16_t)u1.w;
    }
    if (tid < 16) bf_l[tid] = fcb[b * 16 + tid];
  }
  if (tid < 16){
    int col = (tid >> 2) * HDIM + b * 4 + (tid & 3);
    b0_l[tid] = bih0[col] + bhh0[col];
    b1_l[tid] = bih1[col] + bhh1[col];
  }
  {
    int row = tid & 63, uu = tid >> 6;
    int unit = b * 4 + uu;
    c0_l[row][uu] = c0g[row * HDIM + unit];
    c1_l[row][uu] = c0g[BATCH * HDIM + row * HDIM + unit];
  }
  if (tid < 64){
    int unit = b * 4;
    // initial h (parity 0) as packed 8B write-through stores
    float4 v0 = *(const float4*)(hx + tid * HDIM + unit);
    float4 v1 = *(const float4*)(hx + BATCH * HDIM + tid * HDIM + unit);
    bf16_t p0[4] = {(bf16_t)v0.x, (bf16_t)v0.y, (bf16_t)v0.z, (bf16_t)v0.w};
    bf16_t p1[4] = {(bf16_t)v1.x, (bf16_t)v1.y, (bf16_t)v1.z, (bf16_t)v1.w};
    __hip_atomic_store((unsigned long long*)(h0b + tid * HDIM + unit),
                       *(const unsigned long long*)p0, __ATOMIC_RELAXED, __HIP_MEMORY_SCOPE_AGENT);
    __hip_atomic_store((unsigned long long*)(h1b + tid * HDIM + unit),
                       *(const unsigned long long*)p1, __ATOMIC_RELAXED, __HIP_MEMORY_SCOPE_AGENT);
  }
  if (tid < 32){
    // token0 = zeros: block b zeroes its 256B slice (32 x 8B)
    __hip_atomic_store((unsigned long long*)(token + b * 128 + tid * 4), 0ull,
                       __ATOMIC_RELAXED, __HIP_MEMORY_SCOPE_AGENT);
  }

  unsigned bargen = 1;
  grid_barrier(arrive, bargen++);

#pragma unroll 1
  for (int t = 0; t < TSTEPS; ++t){
    const int rp = t & 1, wp = rp ^ 1;
    const bf16_t* h0r = h0b + rp * BATCH * HDIM;
    bf16_t*       h0w = h0b + wp * BATCH * HDIM;
    const bf16_t* h1r = h1b + rp * BATCH * HDIM;
    bf16_t*       h1w = h1b + wp * BATCH * HDIM;
    const int arow = wv * 16 + nl;   // A-operand row for this lane (m = lane&15)

    // ---- phase 1: layer-0 gates (A = [token | h0_prev]) + cell update ----
    {
      f32x4 acc0 = {0.f,0.f,0.f,0.f}, acc1 = {0.f,0.f,0.f,0.f};
      gemm_seg<16>(token + arow * INDIM + q * 8, W0s, 0,  lane, acc0, acc1);
      gemm_seg<32>(h0r   + arow * HDIM  + q * 8, W0s, 16, lane, acc0, acc1);
      f32x4 accv = acc0 + acc1;
      float bias = b0_l[nl];
#pragma unroll
      for (int r = 0; r < 4; ++r) gates_s[wv][q * 4 + r][nl] = accv[r] + bias;
      __syncthreads();
      int row = tid & 63, uu = tid >> 6;
      float pi = gates_s[row >> 4][row & 15][0 * 4 + uu];
      float pf = gates_s[row >> 4][row & 15][1 * 4 + uu];
      float pg = gates_s[row >> 4][row & 15][2 * 4 + uu];
      float po = gates_s[row >> 4][row & 15][3 * 4 + uu];
      float ig = fast_sigmoid(pi), fg = fast_sigmoid(pf);
      float gg = fast_tanh(pg),    og = fast_sigmoid(po);
      float c  = fg * c0_l[row][uu] + ig * gg;
      c0_l[row][uu] = c;
      hstage[row][uu] = (bf16_t)(og * fast_tanh(c));
      __syncthreads();
      if (tid < 64){
        unsigned long long v = *(const unsigned long long*)hstage[tid];
        __hip_atomic_store((unsigned long long*)(h0w + tid * HDIM + b * 4), v,
                           __ATOMIC_RELAXED, __HIP_MEMORY_SCOPE_AGENT);
      }
    }
    grid_barrier(arrive, bargen++);

    // ---- phase 2: layer-1 gates (A = [h0_new | h1_prev]) + cell update ----
    {
      f32x4 acc0 = {0.f,0.f,0.f,0.f}, acc1 = {0.f,0.f,0.f,0.f};
      gemm_seg<32>(h0w + arow * HDIM + q * 8, W1s, 0,  lane, acc0, acc1);
      gemm_seg<32>(h1r + arow * HDIM + q * 8, W1s, 32, lane, acc0, acc1);
      f32x4 accv = acc0 + acc1;
      float bias = b1_l[nl];
#pragma unroll
      for (int r = 0; r < 4; ++r) gates_s[wv][q * 4 + r][nl] = accv[r] + bias;
      __syncthreads();
      int row = tid & 63, uu = tid >> 6;
      float pi = gates_s[row >> 4][row & 15][0 * 4 + uu];
      float pf = gates_s[row >> 4][row & 15][1 * 4 + uu];
      float pg = gates_s[row >> 4][row & 15][2 * 4 + uu];
      float po = gates_s[row >> 4][row & 15][3 * 4 + uu];
      float ig = fast_sigmoid(pi), fg = fast_sigmoid(pf);
      float gg = fast_tanh(pg),    og = fast_sigmoid(po);
      float c  = fg * c1_l[row][uu] + ig * gg;
      c1_l[row][uu] = c;
      hstage[row][uu] = (bf16_t)(og * fast_tanh(c));
      __syncthreads();
      if (tid < 64){
        unsigned long long v = *(const unsigned long long*)hstage[tid];
        __hip_atomic_store((unsigned long long*)(h1w + tid * HDIM + b * 4), v,
                           __ATOMIC_RELAXED, __HIP_MEMORY_SCOPE_AGENT);
      }
    }
    grid_barrier(arrive, bargen++);

    // ---- phase 3: fc + sigmoid -> out[:,t,:] and next token (blocks 0..31) ----
    if (b < 32){
      f32x4 acc0 = {0.f,0.f,0.f,0.f}, acc1 = {0.f,0.f,0.f,0.f};
      gemm_seg<32>(h1w + arow * HDIM + q * 8, WFs, 0, lane, acc0, acc1);
      f32x4 accv = acc0 + acc1;
      int col = b * 16 + nl;
      float bias = bf_l[nl];
#pragma unroll
      for (int r = 0; r < 4; ++r){
        int m = wv * 16 + q * 4 + r;     // C/D: row = (lane>>4)*4 + reg, col = lane&15
        float v = fast_sigmoid(accv[r] + bias);
        out[m * (TSTEPS * INDIM) + t * INDIM + col] = v;   // plain store (harness-only)
        tstage[m][nl] = (bf16_t)v;
      }
      __syncthreads();
      {
        int row = tid >> 2, part = tid & 3;
        unsigned long long v = *(const unsigned long long*)&tstage[row][part * 4];
        __hip_atomic_store((unsigned long long*)(token + row * INDIM + b * 16 + part * 4), v,
                           __ATOMIC_RELAXED, __HIP_MEMORY_SCOPE_AGENT);
      }
    }
    grid_barrier(arrive, bargen++);
  }
}

extern "C" void kernel_launch(void* const* d_in, const int* in_sizes, int n_in,
                              void* d_out, int out_size, void* d_ws, size_t ws_size,
                              hipStream_t stream){
  const float* hx   = (const float*)d_in[1];
  const float* c0g  = (const float*)d_in[2];
  const float* Wih0 = (const float*)d_in[3];
  const float* Whh0 = (const float*)d_in[4];
  const float* bih0 = (const float*)d_in[5];
  const float* bhh0 = (const float*)d_in[6];
  const float* Wih1 = (const float*)d_in[7];
  const float* Whh1 = (const float*)d_in[8];
  const float* bih1 = (const float*)d_in[9];
  const float* bhh1 = (const float*)d_in[10];
  const float* fcw  = (const float*)d_in[11];
  const float* fcb  = (const float*)d_in[12];
  float* out = (float*)d_out;

  // zero barrier flag slots (ws is poisoned 0xAA before every launch)
  hipMemsetAsync(d_ws, 0, 32768, stream);

  void* args[] = { (void*)&hx, (void*)&c0g, (void*)&Wih0, (void*)&Whh0,
                   (void*)&bih0, (void*)&bhh0, (void*)&Wih1, (void*)&Whh1,
                   (void*)&bih1, (void*)&bhh1, (void*)&fcw, (void*)&fcb,
                   (void*)&out, (void*)&d_ws };
  hipLaunchCooperativeKernel((const void*)rnn_persistent, dim3(NBLK), dim3(NTHR),
                             args, 0, stream);
}